// Round 6
// baseline (317.064 us; speedup 1.0000x reference)
//
#include <hip/hip_runtime.h>

#define HDIM 4096
#define NIN 17
#define NA 4

using f4 = __attribute__((ext_vector_type(4))) float;

// ---- config ----
constexpr int TB1 = 1024;                 // 16 waves/block, 1 block/CU
constexpr int CPB = 16;                   // columns per block (64B row segment)
constexpr int NBLK1 = HDIM / CPB;         // 256 blocks = 1 per CU
constexpr int RPP = TB1 / 4;              // 256 rows per pass (4 threads/row)
constexpr int NPASS = HDIM / RPP;         // 16 passes

// ============================================================================
// Single plain kernel (no cooperative launch, no grid sync).
// Block b owns columns [16b, 16b+16).
//
// Phase A: slab matvec -> h for its 16 cols (j only needs column j!).
//   w/alpha: NONTEMPORAL loads (single-use; keep them OUT of L3 so the 64 MB
//   hebb stream — loaded normally — stays L3-resident across iterations; this
//   is what made R3's matvec fetch 98 MB instead of 192 MB).
// Heads: 16-lane shfl reduce + 5 atomicAdds; last block (atomic counter)
//   finalizes softmax+value in-kernel.
// Phase B: update OWN hebb slab (needs only own h): reverse row order
//   (last-read rows are L2-hot), scalar NT stores (out+4101 base is only
//   4B-aligned; L2 write-combining merges to full lines).
// ============================================================================
__global__ __launch_bounds__(TB1, 1)
void k_main(const float* __restrict__ w, const float* __restrict__ alpha,
            const float* __restrict__ hebb, const float* __restrict__ hidden,
            const float* __restrict__ x, const float* __restrict__ i2h_w,
            const float* __restrict__ i2h_b,
            const float* __restrict__ h2o_w, const float* __restrict__ h2o_b,
            const float* __restrict__ h2v_w, const float* __restrict__ h2v_b,
            const float* __restrict__ eta,
            float* __restrict__ out, float* __restrict__ acc5,
            unsigned* __restrict__ cnt) {
    const int tid = threadIdx.x;
    const int q = tid & 3;                    // float4-quad within the 16-col slab
    const int rw = tid >> 2;                  // row within pass (0..255)
    const int colq = blockIdx.x * CPB + q * 4;

    // ---------------- phase A: slab matvec ----------------------------------
    f4 acc = {0.f, 0.f, 0.f, 0.f};
#pragma unroll 4
    for (int p = 0; p < NPASS; ++p) {
        const int r = p * RPP + rw;
        const size_t off = (size_t)r * HDIM + colq;
        const f4 wv = __builtin_nontemporal_load((const f4*)(w + off));
        const f4 av = __builtin_nontemporal_load((const f4*)(alpha + off));
        const f4 bv = *(const f4*)(hebb + off);   // allocating: re-read in phase B + next iter
        acc += hidden[r] * (wv + av * bv);
    }

    __shared__ f4 red[TB1];                   // 16 KB
    red[tid] = acc;
    __syncthreads();
    for (int s = TB1 / 2; s >= 4; s >>= 1) {  // strides multiple of 4: stay in col-quad
        if (tid < s) red[tid] += red[tid + s];
        __syncthreads();
    }

    __shared__ float hsh[CPB];
    if (tid < CPB) {
        const int j = blockIdx.x * CPB + tid; // col = (tid>>2)*4 + (tid&3) = tid
        float z = red[tid >> 2][tid & 3] + i2h_b[j];
#pragma unroll
        for (int k = 0; k < NIN; ++k) z += x[k] * i2h_w[j * NIN + k];
        const float h = tanhf(z);
        out[5 + j] = h;
        hsh[tid] = h;
        // head-dot partials over this block's 16 cols
        float d[NA + 1];
#pragma unroll
        for (int a = 0; a < NA; ++a) d[a] = h * h2o_w[(size_t)a * HDIM + j];
        d[NA] = h * h2v_w[j];
#pragma unroll
        for (int a = 0; a <= NA; ++a) {
            float v = d[a];
#pragma unroll
            for (int sft = 8; sft > 0; sft >>= 1) v += __shfl_down(v, sft, 16);
            if (tid == 0) atomicAdd(acc5 + a, v);
        }
    }
    __syncthreads();

    // ---------------- last-block head finalize ------------------------------
    if (tid == 0) {
        __threadfence();                          // release our acc5 adds
        if (atomicAdd(cnt, 1u) == NBLK1 - 1) {    // I'm the last block
            float res[NA + 1];
#pragma unroll
            for (int a = 0; a <= NA; ++a) res[a] = atomicAdd(acc5 + a, 0.f); // coherent read
            float o[NA];
            float mx = -1e30f;
#pragma unroll
            for (int a = 0; a < NA; ++a) { o[a] = res[a] + h2o_b[a]; mx = fmaxf(mx, o[a]); }
            float se = 0.f;
#pragma unroll
            for (int a = 0; a < NA; ++a) { o[a] = __expf(o[a] - mx); se += o[a]; }
#pragma unroll
            for (int a = 0; a < NA; ++a) out[a] = o[a] / se;
            out[NA] = res[NA] + h2v_b[0];
        }
    }

    // ---------------- phase B: own-slab hebb update (no sync needed) --------
    // hebb_new[i][j] = (1-e)*hebb[i][j] + e*hidden[i]*h[j], j in own 16 cols.
    const float e = eta[0];
    const float om = 1.f - e;
    const int cB = tid & 15;                  // col within slab
    const int rB0 = tid >> 4;                 // 0..63: row offset within step
    const int j = blockIdx.x * CPB + cB;
    const float hj = e * hsh[cB];
    const float* __restrict__ hin = hebb + j;
    float* __restrict__ outp = out + 5 + HDIM + j;   // element offset 4101 + j
    // reverse order: rows 4032..4095 were read last in phase A -> L2-hot first
#pragma unroll 8
    for (int s = 63; s >= 0; --s) {
        const int r = s * 64 + rB0;
        const size_t off = (size_t)r * HDIM;
        const float v = om * hin[off] + hidden[r] * hj;
        __builtin_nontemporal_store(v, outp + off);
    }
}

extern "C" void kernel_launch(void* const* d_in, const int* in_sizes, int n_in,
                              void* d_out, int out_size, void* d_ws, size_t ws_size,
                              hipStream_t stream) {
    const float* x      = (const float*)d_in[0];
    const float* hidden = (const float*)d_in[1];
    const float* hebb   = (const float*)d_in[2];
    const float* i2h_w  = (const float*)d_in[3];
    const float* i2h_b  = (const float*)d_in[4];
    const float* w      = (const float*)d_in[5];
    const float* alpha  = (const float*)d_in[6];
    const float* eta    = (const float*)d_in[7];
    const float* h2o_w  = (const float*)d_in[8];
    const float* h2o_b  = (const float*)d_in[9];
    const float* h2v_w  = (const float*)d_in[10];
    const float* h2v_b  = (const float*)d_in[11];
    float* out = (float*)d_out;

    // workspace: acc5[8] floats + counter
    float* acc5 = (float*)d_ws;
    unsigned* cnt = (unsigned*)(acc5 + 8);

    hipMemsetAsync(acc5, 0, 48, stream);   // zero acc5 + counter each iteration

    k_main<<<NBLK1, TB1, 0, stream>>>(w, alpha, hebb, hidden, x, i2h_w, i2h_b,
                                      h2o_w, h2o_b, h2v_w, h2v_b, eta,
                                      out, acc5, cnt);
}

// Round 7
// 258.784 us; speedup vs baseline: 1.2252x; 1.2252x over previous
//
#include <hip/hip_runtime.h>

#define HDIM 4096
#define NIN 17
#define NA 4

using f4 = __attribute__((ext_vector_type(4))) float;

// ---- config ----
constexpr int TB = 256;                 // threads per block
constexpr int CPT = 4;                  // columns per thread (one float4)
constexpr int BXC = HDIM / (TB * CPT);  // 4 column groups
constexpr int NCHUNK = 1024;            // row chunks (4096 blocks total)
constexpr int RPC = HDIM / NCHUNK;      // 4 rows per chunk
constexpr size_t NELEM = (size_t)HDIM * HDIM;

// Kernel A (R3-proven, 52 us): partial sums of hidden @ (w + alpha*hebb).
// 4096 blocks + 12-load burst; w/alpha NONTEMPORAL (single-use -> keep out of
// L3 so hebb stays L3-resident across iterations; R3 measured FETCH 98 MB of
// 208 MB touched). Also zeroes acc5 + cnt for the downstream kernels.
__global__ void k_matvec(const float* __restrict__ w, const float* __restrict__ alpha,
                         const float* __restrict__ hebb, const float* __restrict__ hidden,
                         float* __restrict__ partial, float* __restrict__ acc5,
                         unsigned* __restrict__ cnt) {
    if (blockIdx.x == 0 && blockIdx.y == 0 && threadIdx.x < 9) {
        if (threadIdx.x < 8) acc5[threadIdx.x] = 0.f;
        else *cnt = 0u;
    }
    const int col0 = (blockIdx.x * TB + threadIdx.x) * CPT;
    const int row0 = blockIdx.y * RPC;
    const size_t base = (size_t)row0 * HDIM + col0;

    f4 wv[RPC], av[RPC], bv[RPC];
#pragma unroll
    for (int r = 0; r < RPC; ++r) {
        const size_t off = base + (size_t)r * HDIM;
        wv[r] = __builtin_nontemporal_load((const f4*)(w + off));
        av[r] = __builtin_nontemporal_load((const f4*)(alpha + off));
        bv[r] = *(const f4*)(hebb + off);
    }
    f4 acc = {0.f, 0.f, 0.f, 0.f};
#pragma unroll
    for (int r = 0; r < RPC; ++r) {
        const float hv = hidden[row0 + r];
        acc += hv * (wv[r] + av[r] * bv[r]);
    }
    *(f4*)(partial + (size_t)blockIdx.y * HDIM + col0) = acc;
}

// Kernel B: reduce 1024 partials per column -> h = tanh(i2h + matvec);
// fused heads (shfl + atomicAdd) + last-block softmax/value finalize.
constexpr int HC = 32;                // cols per block
constexpr int HGRP = TB / HC;         // 8 groups
constexpr int HCPG = NCHUNK / HGRP;   // 128 chunks per group

__global__ void k_hact(const float* __restrict__ partial, const float* __restrict__ x,
                       const float* __restrict__ i2h_w, const float* __restrict__ i2h_b,
                       const float* __restrict__ h2o_w, const float* __restrict__ h2o_b,
                       const float* __restrict__ h2v_w, const float* __restrict__ h2v_b,
                       float* __restrict__ h_f, float* __restrict__ h_out,
                       float* __restrict__ acc5, unsigned* __restrict__ cnt,
                       float* __restrict__ out) {
    const int tid = threadIdx.x;
    const int lane = tid & (HC - 1);
    const int grp = tid >> 5;
    const int col = blockIdx.x * HC + lane;

    float s = 0.f;
    const float* p = partial + (size_t)(grp * HCPG) * HDIM + col;
#pragma unroll 16
    for (int c = 0; c < HCPG; ++c) s += p[(size_t)c * HDIM];

    __shared__ float red[TB];
    red[tid] = s;
    __syncthreads();
    for (int st = TB / 2; st >= HC; st >>= 1) {
        if (tid < st) red[tid] += red[tid + st];
        __syncthreads();
    }
    if (tid < HC) {
        float z = red[tid] + i2h_b[col];
#pragma unroll
        for (int k = 0; k < NIN; ++k) z += x[k] * i2h_w[col * NIN + k];
        const float h = tanhf(z);
        h_f[col] = h;
        h_out[col] = h;
        float d[NA + 1];
#pragma unroll
        for (int a = 0; a < NA; ++a) d[a] = h * h2o_w[(size_t)a * HDIM + col];
        d[NA] = h * h2v_w[col];
#pragma unroll
        for (int a = 0; a <= NA; ++a) {
            float v = d[a];
#pragma unroll
            for (int sft = 16; sft > 0; sft >>= 1) v += __shfl_down(v, sft, 32);
            if (lane == 0) atomicAdd(acc5 + a, v);
        }
    }
    // last-block finalize (R6-proven pattern): removes the k_finish dispatch
    if (tid == 0) {
        __threadfence();
        if (atomicAdd(cnt, 1u) == (HDIM / HC) - 1) {
            float res[NA + 1];
#pragma unroll
            for (int a = 0; a <= NA; ++a) res[a] = atomicAdd(acc5 + a, 0.f);
            float o[NA];
            float mx = -1e30f;
#pragma unroll
            for (int a = 0; a < NA; ++a) { o[a] = res[a] + h2o_b[a]; mx = fmaxf(mx, o[a]); }
            float se = 0.f;
#pragma unroll
            for (int a = 0; a < NA; ++a) { o[a] = __expf(o[a] - mx); se += o[a]; }
#pragma unroll
            for (int a = 0; a < NA; ++a) out[a] = o[a] / se;
            out[NA] = res[NA] + h2v_b[0];
        }
    }
}

// Kernel C: hebb_new = (1-eta)*hebb + eta*outer(hidden, h).
// Rebuilt for ILP: 4 quads (64 B) per thread, wave-contiguous mapping, all 8
// loads issued before the 4 aligned NT f4 stores. 4t+3 trick: quad k covers
// elements s..s+3, s = 4k+3, so out+4101+s is 16B-aligned. hebb read NORMAL
// (L3-hot from matvec; needed again next iteration). Head {0,1,2} and tail
// {NELEM-1} handled by thread 0.
constexpr size_t NQK = 4194303;           // quads: s+3 < NELEM  ->  k < NQK
constexpr int HEB_BLK = 4096;             // x 256 threads x 4 quads = covers NQK

__global__ void k_hebb(const float* __restrict__ hebb, const float* __restrict__ hidden,
                       const float* __restrict__ h_f, const float* __restrict__ eta,
                       float* __restrict__ hebb_out) {
    const int tid = threadIdx.x;
    const size_t gt = (size_t)blockIdx.x * TB + tid;
    const size_t wid = gt >> 6;           // global wave id
    const int lane = tid & 63;
    const float e = eta[0];
    const float om = 1.f - e;

    if (gt == 0) {  // head elements 0,1,2 (row 0) + tail element NELEM-1
        const float hv0 = e * hidden[0];
        hebb_out[0] = om * hebb[0] + hv0 * h_f[0];
        hebb_out[1] = om * hebb[1] + hv0 * h_f[1];
        hebb_out[2] = om * hebb[2] + hv0 * h_f[2];
        hebb_out[NELEM - 1] = om * hebb[NELEM - 1] + e * hidden[HDIM - 1] * h_f[HDIM - 1];
    }

    // 4 quads per thread; wave covers 256 consecutive quads (16 KB) per issue
    size_t k[4];
    bool ok[4];
    float b0[4];
    f4 bv[4];
#pragma unroll
    for (int q = 0; q < 4; ++q) {
        k[q] = wid * 256 + (size_t)lane + (size_t)q * 64;
        ok[q] = k[q] < NQK;
    }
#pragma unroll
    for (int q = 0; q < 4; ++q) {
        if (ok[q]) {
            const size_t s = 4 * k[q] + 3;
            b0[q] = hebb[s];                       // 4B-aligned scalar
            bv[q] = *(const f4*)(hebb + s + 1);    // 16B-aligned
        }
    }
#pragma unroll
    for (int q = 0; q < 4; ++q) {
        if (ok[q]) {
            const size_t s = 4 * k[q] + 3;
            const float b[4] = {b0[q], bv[q].x, bv[q].y, bv[q].z};
            f4 v;
#pragma unroll
            for (int kk = 0; kk < 4; ++kk) {
                const size_t m = s + (size_t)kk;
                const int i = (int)(m >> 12);
                const int jj = (int)(m & (HDIM - 1));
                v[kk] = om * b[kk] + e * hidden[i] * h_f[jj];
            }
            __builtin_nontemporal_store(v, (f4*)(hebb_out + s));  // 16B-aligned
        }
    }
}

extern "C" void kernel_launch(void* const* d_in, const int* in_sizes, int n_in,
                              void* d_out, int out_size, void* d_ws, size_t ws_size,
                              hipStream_t stream) {
    const float* x      = (const float*)d_in[0];
    const float* hidden = (const float*)d_in[1];
    const float* hebb   = (const float*)d_in[2];
    const float* i2h_w  = (const float*)d_in[3];
    const float* i2h_b  = (const float*)d_in[4];
    const float* w      = (const float*)d_in[5];
    const float* alpha  = (const float*)d_in[6];
    const float* eta    = (const float*)d_in[7];
    const float* h2o_w  = (const float*)d_in[8];
    const float* h2o_b  = (const float*)d_in[9];
    const float* h2v_w  = (const float*)d_in[10];
    const float* h2v_b  = (const float*)d_in[11];
    float* out = (float*)d_out;

    // out layout: activout[4] | valueout[1] | h[4096] | hebb_new[4096*4096]
    float* h_out    = out + 5;
    float* hebb_out = out + 5 + HDIM;

    // partial[NCHUNK][HDIM] (16 MB) in the hebb_out region as scratch:
    // consumed by k_hact, then fully overwritten by k_hebb (R3-proven).
    float* partial = out + 8192;

    float* h_f  = (float*)d_ws;        // HDIM floats
    float* acc5 = h_f + HDIM;          // 8 floats (5 used)
    unsigned* cnt = (unsigned*)(acc5 + 8);

    k_matvec<<<dim3(BXC, NCHUNK), TB, 0, stream>>>(w, alpha, hebb, hidden, partial, acc5, cnt);
    k_hact<<<HDIM / HC, TB, 0, stream>>>(partial, x, i2h_w, i2h_b, h2o_w, h2o_b,
                                         h2v_w, h2v_b, h_f, h_out, acc5, cnt, out);
    k_hebb<<<HEB_BLK, TB, 0, stream>>>(hebb, hidden, h_f, eta, hebb_out);
}